// Round 11
// baseline (147.636 us; speedup 1.0000x reference)
//
#include <hip/hip_runtime.h>

#define B_ 4
#define S_ 512
#define T_ 512
#define D_ 256
#define NSRC (B_ * S_)            // 2048 source rows
#define NROW 4096                 // src rows + tgt rows
#define K2F 2.8853900817779268f   // 2*log2(e): exp2(x*K2F) = e^(2x)

typedef __attribute__((ext_vector_type(8))) short short8;   // 8 bf16
typedef __attribute__((ext_vector_type(4))) float f32x4;
typedef __attribute__((ext_vector_type(2))) float f32x2;

__device__ __forceinline__ unsigned short f2bf(float f) {
    union { float f; unsigned u; } v; v.f = f;
    unsigned r = v.u + 0x7FFF + ((v.u >> 16) & 1);   // RNE
    return (unsigned short)(r >> 16);
}

// ---------------------------------------------------------------------------
// K1: ysyt+prob (VERBATIM R9, proven). 768 blocks x 256 thr.
//  blocks 0..255: ysyt with per-block W-slab LDS transpose; writes
//                 yst[d][global_row] f32 (transposed, free via MFMA D-layout).
//  blocks 256..767: prob softmax, 4 rows each.
// ---------------------------------------------------------------------------
__global__ __launch_bounds__(256) void ysyt_kernel(
    const float* __restrict__ src, const float* __restrict__ tgt,
    const float* __restrict__ Wsrc, const float* __restrict__ Wtgt,
    const float* __restrict__ Wp,  const float* __restrict__ bp,
    const float* __restrict__ bsrc, const float* __restrict__ btgt,
    float* __restrict__ yst, float* __restrict__ out)
{
    __shared__ unsigned short lwt[16384];    // 32 KB
    const int bid = blockIdx.x, tid = threadIdx.x;
    const int lane = tid & 63, w = tid >> 6;

    if (bid < 256) {
        const int rowblk = bid >> 2, colq = bid & 3;
        const int R0 = rowblk * 64;
        const int n = lane & 15, quad = lane >> 4;
        const int mat = (R0 >= NSRC) ? 1 : 0;
        const float* bias = mat ? btgt : bsrc;
        const float* Wm = mat ? Wtgt : Wsrc;
        const float* xb = mat ? &tgt[(R0 - NSRC) * D_] : &src[R0 * D_];

        {
            const int r = tid;
            const int ksr = r >> 5, qr = (r >> 3) & 3, jr = r & 7;
            const int wbase = ksr * 512 + qr * 8 + jr;
            #pragma unroll 4
            for (int i = 0; i < 16; i++) {
                float4 v = *(const float4*)&Wm[r * D_ + colq * 64 + 4 * i];
                const int cc = 4 * i;
                lwt[((cc + 0) >> 4) * 4096 + ((cc + 0) & 15) * 32 + wbase] = f2bf(v.x);
                lwt[((cc + 1) >> 4) * 4096 + ((cc + 1) & 15) * 32 + wbase] = f2bf(v.y);
                lwt[((cc + 2) >> 4) * 4096 + ((cc + 2) & 15) * 32 + wbase] = f2bf(v.z);
                lwt[((cc + 3) >> 4) * 4096 + ((cc + 3) & 15) * 32 + wbase] = f2bf(v.w);
            }
        }

        short8 af[8];
        #pragma unroll
        for (int ks = 0; ks < 8; ks++) {
            const float* p = &xb[(w * 16 + n) * D_ + ks * 32 + quad * 8];
            float4 u0 = *(const float4*)p;
            float4 u1 = *(const float4*)(p + 4);
            short8 v;
            v[0] = (short)f2bf(u0.x); v[1] = (short)f2bf(u0.y);
            v[2] = (short)f2bf(u0.z); v[3] = (short)f2bf(u0.w);
            v[4] = (short)f2bf(u1.x); v[5] = (short)f2bf(u1.y);
            v[6] = (short)f2bf(u1.z); v[7] = (short)f2bf(u1.w);
            af[ks] = v;
        }
        __syncthreads();

        #pragma unroll
        for (int gc = 0; gc < 4; gc++) {
            const int gcol = colq * 4 + gc;
            const unsigned short* bp2 = &lwt[gc * 4096 + n * 32 + quad * 8];
            short8 bf[8];
            #pragma unroll
            for (int ks = 0; ks < 8; ks++) bf[ks] = *(const short8*)&bp2[ks * 512];
            f32x4 a4 = {0.f, 0.f, 0.f, 0.f};
            #pragma unroll
            for (int ks = 0; ks < 8; ks++)
                a4 = __builtin_amdgcn_mfma_f32_16x16x32_bf16(af[ks], bf[ks], a4, 0, 0, 0);
            const float bv = bias[gcol * 16 + n];
            float4 o;
            o.x = __builtin_amdgcn_exp2f((a4[0] + bv) * K2F);
            o.y = __builtin_amdgcn_exp2f((a4[1] + bv) * K2F);
            o.z = __builtin_amdgcn_exp2f((a4[2] + bv) * K2F);
            o.w = __builtin_amdgcn_exp2f((a4[3] + bv) * K2F);
            *(float4*)&yst[(gcol * 16 + n) * NROW + R0 + w * 16 + quad * 4] = o;
        }
    } else {
        int row  = (bid - 256) * 4 + w;
        float p0 = 0.f, p1 = 0.f;
        #pragma unroll
        for (int i = 0; i < 4; i++) {
            int d = lane + i * 64;
            float v = tgt[row * D_ + d];
            float2 wv = *(const float2*)&Wp[d * 2];
            p0 = fmaf(v, wv.x, p0);
            p1 = fmaf(v, wv.y, p1);
        }
        #pragma unroll
        for (int off = 32; off > 0; off >>= 1) {
            p0 += __shfl_down(p0, off, 64);
            p1 += __shfl_down(p1, off, 64);
        }
        if (lane == 0) {
            const float L2E = 1.4426950408889634f;
            float l0 = p0 + bp[0], l1 = p1 + bp[1];
            float e10 = __builtin_amdgcn_exp2f((l1 - l0) * L2E);
            float e01 = __builtin_amdgcn_exp2f((l0 - l1) * L2E);
            out[B_ * T_ * S_ + row * 2 + 0] = __builtin_amdgcn_rcpf(1.f + e10);
            out[B_ * T_ * S_ + row * 2 + 1] = __builtin_amdgcn_rcpf(1.f + e01);
        }
    }
}

// ---------------------------------------------------------------------------
// K2: genp v6 — LDS-staged, 4s x 4t per thread, single-barrier d-quarters.
// R10 lesson: zero-LDS streaming = 805MB from L2 -> >=23us L2-BW floor; LDS
// tile is mandatory. R7 lesson: 2s x {2t,4t} both ~31us (LDS floor 20.5/15);
// 4s x 4t halves the LDS instr floor to 10.2us: per wave-d ONE b128 (s) +
// ONE b128 (t) covers 1024 terms.
// Tile 64s x 64t x 64d (d-quarter per block); grid (8,8,16) = 1024 blocks
// = 4 blk/CU (LDS 34.8KB), 16 waves/CU; ONE stage + ONE barrier per block
// (no dbuf loop -> no convoy; staging of one block overlaps compute of the
// other 3). d-quarters combine via unsafeAtomicAdd (validated R10: passed).
// Strides 68 (R6 pow-2 lesson); all LDS reads <=2-way aliasing (free, m136).
// genP = C0 - 2 * sum_d w_d / (1 + ys*yt),  C0 = sum w + b_res (dq==0 only).
// ---------------------------------------------------------------------------
__global__ __launch_bounds__(256) void genp_kernel(
    const float* __restrict__ yst,   // [256][4096]
    const float* __restrict__ Wres, const float* __restrict__ bres,
    float* __restrict__ out)
{
    __shared__ float lys[64][68];    // 17.4 KB
    __shared__ float lyt[64][68];    // 17.4 KB

    const int tid = threadIdx.x;
    const int lane = tid & 63;
    const int s0 = blockIdx.x * 64;
    const int t0 = blockIdx.y * 64;
    const int b  = blockIdx.z >> 2;
    const int dq = blockIdx.z & 3;
    const int d0 = dq * 64;
    const int m  = tid & 15;             // s = s0 + 4m .. 4m+3
    const int g  = tid >> 4;             // t = t0 + 4g .. 4g+3

    // ---- stage 64d x (64s + 64t) from yst (32 KB, coalesced float4) ----
    {
        const int r = tid >> 2, q = tid & 3;       // row 0..63, quarter 0..3
        const int sbase = b * S_ + s0;
        const int tbase = NSRC + b * T_ + t0;
        #pragma unroll
        for (int j = 0; j < 4; j++) {
            float4 vs = *(const float4*)&yst[(size_t)(d0 + r) * NROW + sbase + q * 16 + 4 * j];
            float4 vt = *(const float4*)&yst[(size_t)(d0 + r) * NROW + tbase + q * 16 + 4 * j];
            *(float4*)&lys[r][q * 16 + 4 * j] = vs;
            *(float4*)&lyt[r][q * 16 + 4 * j] = vt;
        }
    }
    __syncthreads();

    f32x2 acc[4][2];                     // [t-idx i][s-pair jp]
    #pragma unroll
    for (int i = 0; i < 4; i++) {
        acc[i][0] = (f32x2){0.f, 0.f};
        acc[i][1] = (f32x2){0.f, 0.f};
    }
    const f32x2 one2 = {1.f, 1.f};

    #pragma unroll 4
    for (int kq = 0; kq < 16; kq++) {
        const int dk = 4 * kq;
        float4 sA[4], tA[4];
        #pragma unroll
        for (int k = 0; k < 4; k++) {
            sA[k] = *(const float4*)&lys[dk + k][4 * m];   // 4 s-values at d=dk+k
            tA[k] = *(const float4*)&lyt[dk + k][4 * g];   // 4 t-values at d=dk+k
        }
        const float w0 = Wres[d0 + dk + 0], w1 = Wres[d0 + dk + 1];
        const float w2 = Wres[d0 + dk + 2], w3 = Wres[d0 + dk + 3];
        const f32x2 wv0 = {w0, w0}, wv1 = {w1, w1};
        const f32x2 wv2 = {w2, w2}, wv3 = {w3, w3};

        // 4-term rcp fold per (t-component, s-pair); compile-time selects.
        #define FOLD(TT, COMP) {                                             \
            const f32x2 c0v = {tA[0].COMP, tA[0].COMP};                      \
            const f32x2 c1v = {tA[1].COMP, tA[1].COMP};                      \
            const f32x2 c2v = {tA[2].COMP, tA[2].COMP};                      \
            const f32x2 c3v = {tA[3].COMP, tA[3].COMP};                      \
            _Pragma("unroll")                                                \
            for (int jp = 0; jp < 2; jp++) {                                 \
                const f32x2 a0 = jp ? (f32x2){sA[0].z, sA[0].w}              \
                                    : (f32x2){sA[0].x, sA[0].y};             \
                const f32x2 a1 = jp ? (f32x2){sA[1].z, sA[1].w}              \
                                    : (f32x2){sA[1].x, sA[1].y};             \
                const f32x2 a2 = jp ? (f32x2){sA[2].z, sA[2].w}              \
                                    : (f32x2){sA[2].x, sA[2].y};             \
                const f32x2 a3 = jp ? (f32x2){sA[3].z, sA[3].w}              \
                                    : (f32x2){sA[3].x, sA[3].y};             \
                f32x2 dd0 = a0 * c0v + one2;                                 \
                f32x2 dd1 = a1 * c1v + one2;                                 \
                f32x2 dd2 = a2 * c2v + one2;                                 \
                f32x2 dd3 = a3 * c3v + one2;                                 \
                f32x2 p01 = dd0 * dd1;                                       \
                f32x2 p23 = dd2 * dd3;                                       \
                f32x2 den = p01 * p23;                                       \
                f32x2 u01 = dd1 * wv0; u01 = dd0 * wv1 + u01;                \
                f32x2 u23 = dd3 * wv2; u23 = dd2 * wv3 + u23;                \
                f32x2 num = u01 * p23; num = u23 * p01 + num;                \
                f32x2 r;                                                     \
                r.x = __builtin_amdgcn_rcpf(den.x);                          \
                r.y = __builtin_amdgcn_rcpf(den.y);                          \
                acc[TT][jp] = num * r + acc[TT][jp];                         \
            }                                                                \
        }
        FOLD(0, x) FOLD(1, y) FOLD(2, z) FOLD(3, w)
        #undef FOLD
    }

    // C0 per-wave (butterfly -> all lanes); only the dq==0 quarter adds it
    float cw = Wres[lane] + Wres[lane + 64] + Wres[lane + 128] + Wres[lane + 192];
    #pragma unroll
    for (int off = 32; off > 0; off >>= 1) cw += __shfl_xor(cw, off, 64);
    const float C0 = (dq == 0) ? (cw + bres[0]) : 0.f;

    #pragma unroll
    for (int i = 0; i < 4; i++) {
        float* orow = &out[(size_t)(b * T_ + t0 + 4 * g + i) * S_ + s0 + 4 * m];
        unsafeAtomicAdd(&orow[0], C0 - 2.f * acc[i][0].x);
        unsafeAtomicAdd(&orow[1], C0 - 2.f * acc[i][0].y);
        unsafeAtomicAdd(&orow[2], C0 - 2.f * acc[i][1].x);
        unsafeAtomicAdd(&orow[3], C0 - 2.f * acc[i][1].y);
    }
}

extern "C" void kernel_launch(void* const* d_in, const int* in_sizes, int n_in,
                              void* d_out, int out_size, void* d_ws, size_t ws_size,
                              hipStream_t stream) {
    const float* source = (const float*)d_in[0];
    const float* target = (const float*)d_in[1];
    const float* W_src  = (const float*)d_in[2];
    const float* b_src  = (const float*)d_in[3];
    const float* W_tgt  = (const float*)d_in[4];
    const float* b_tgt  = (const float*)d_in[5];
    const float* W_res  = (const float*)d_in[6];
    const float* b_res  = (const float*)d_in[7];
    const float* W_prob = (const float*)d_in[8];
    const float* b_prob = (const float*)d_in[9];
    float* out = (float*)d_out;

    float* yst = (float*)d_ws;                 // [256][4096] f32 = 4 MB

    ysyt_kernel<<<768, 256, 0, stream>>>(source, target, W_src, W_tgt,
                                         W_prob, b_prob, b_src, b_tgt,
                                         yst, out);
    genp_kernel<<<dim3(8, 8, 16), 256, 0, stream>>>(yst, W_res, b_res, out);
}

// Round 12
// 108.423 us; speedup vs baseline: 1.3617x; 1.3617x over previous
//
#include <hip/hip_runtime.h>

#define B_ 4
#define S_ 512
#define T_ 512
#define D_ 256
#define NSRC (B_ * S_)            // 2048 source rows
#define NROW 4096                 // src rows + tgt rows
#define K2F 2.8853900817779268f   // 2*log2(e): exp2(x*K2F) = e^(2x)

typedef __attribute__((ext_vector_type(8))) short short8;      // 8 bf16
typedef __attribute__((ext_vector_type(8))) _Float16 half8;    // 8 f16
typedef __attribute__((ext_vector_type(4))) float f32x4;
typedef __attribute__((ext_vector_type(2))) float f32x2;

__device__ __forceinline__ unsigned short f2bf(float f) {
    union { float f; unsigned u; } v; v.f = f;
    unsigned r = v.u + 0x7FFF + ((v.u >> 16) & 1);   // RNE
    return (unsigned short)(r >> 16);
}

// ---------------------------------------------------------------------------
// K1: ysyt+prob. 768 blocks x 256 thr.
//  blocks 0..255: ysyt (W-slab LDS transpose + MFMA + exp2, proven R9), now
//    writing ROW-MAJOR f16: ytr[row][d] via LDS bounce (R6-proven pattern).
//    f16 safe: e^{2u} <= ~e^9 ~ 8100 << 65504; clamp 60000 guards the tail
//    (inf would NaN the genp rcp-fold). Rel err 5e-4 -> output err ~1e-3.
//  blocks 256..767: prob softmax, 4 rows each (verbatim).
// ---------------------------------------------------------------------------
__global__ __launch_bounds__(256) void ysyt_kernel(
    const float* __restrict__ src, const float* __restrict__ tgt,
    const float* __restrict__ Wsrc, const float* __restrict__ Wtgt,
    const float* __restrict__ Wp,  const float* __restrict__ bp,
    const float* __restrict__ bsrc, const float* __restrict__ btgt,
    _Float16* __restrict__ ytr, float* __restrict__ out)
{
    __shared__ unsigned short lwt[16384];    // 32 KB
    __shared__ _Float16 ltb[64][72];         // 9.2 KB bounce tile
    const int bid = blockIdx.x, tid = threadIdx.x;
    const int lane = tid & 63, w = tid >> 6;

    if (bid < 256) {
        const int rowblk = bid >> 2, colq = bid & 3;
        const int R0 = rowblk * 64;
        const int n = lane & 15, quad = lane >> 4;
        const int mat = (R0 >= NSRC) ? 1 : 0;
        const float* bias = mat ? btgt : bsrc;
        const float* Wm = mat ? Wtgt : Wsrc;
        const float* xb = mat ? &tgt[(R0 - NSRC) * D_] : &src[R0 * D_];

        {   // W-slab transpose -> lwt (verbatim R9)
            const int r = tid;
            const int ksr = r >> 5, qr = (r >> 3) & 3, jr = r & 7;
            const int wbase = ksr * 512 + qr * 8 + jr;
            #pragma unroll 4
            for (int i = 0; i < 16; i++) {
                float4 v = *(const float4*)&Wm[r * D_ + colq * 64 + 4 * i];
                const int cc = 4 * i;
                lwt[((cc + 0) >> 4) * 4096 + ((cc + 0) & 15) * 32 + wbase] = f2bf(v.x);
                lwt[((cc + 1) >> 4) * 4096 + ((cc + 1) & 15) * 32 + wbase] = f2bf(v.y);
                lwt[((cc + 2) >> 4) * 4096 + ((cc + 2) & 15) * 32 + wbase] = f2bf(v.z);
                lwt[((cc + 3) >> 4) * 4096 + ((cc + 3) & 15) * 32 + wbase] = f2bf(v.w);
            }
        }

        short8 af[8];
        #pragma unroll
        for (int ks = 0; ks < 8; ks++) {
            const float* p = &xb[(w * 16 + n) * D_ + ks * 32 + quad * 8];
            float4 u0 = *(const float4*)p;
            float4 u1 = *(const float4*)(p + 4);
            short8 v;
            v[0] = (short)f2bf(u0.x); v[1] = (short)f2bf(u0.y);
            v[2] = (short)f2bf(u0.z); v[3] = (short)f2bf(u0.w);
            v[4] = (short)f2bf(u1.x); v[5] = (short)f2bf(u1.y);
            v[6] = (short)f2bf(u1.z); v[7] = (short)f2bf(u1.w);
            af[ks] = v;
        }
        __syncthreads();

        #pragma unroll
        for (int gc = 0; gc < 4; gc++) {
            const int gcol = colq * 4 + gc;
            const unsigned short* bp2 = &lwt[gc * 4096 + n * 32 + quad * 8];
            short8 bf[8];
            #pragma unroll
            for (int ks = 0; ks < 8; ks++) bf[ks] = *(const short8*)&bp2[ks * 512];
            f32x4 a4 = {0.f, 0.f, 0.f, 0.f};
            #pragma unroll
            for (int ks = 0; ks < 8; ks++)
                a4 = __builtin_amdgcn_mfma_f32_16x16x32_bf16(af[ks], bf[ks], a4, 0, 0, 0);
            const float bv = bias[gcol * 16 + n];
            // lane holds rows rl..rl+3 at local d-col dl -> bounce to LDS f16
            const int rl = w * 16 + quad * 4;
            const int dl = gc * 16 + n;
            ltb[rl + 0][dl] = (_Float16)fminf(__builtin_amdgcn_exp2f((a4[0] + bv) * K2F), 60000.f);
            ltb[rl + 1][dl] = (_Float16)fminf(__builtin_amdgcn_exp2f((a4[1] + bv) * K2F), 60000.f);
            ltb[rl + 2][dl] = (_Float16)fminf(__builtin_amdgcn_exp2f((a4[2] + bv) * K2F), 60000.f);
            ltb[rl + 3][dl] = (_Float16)fminf(__builtin_amdgcn_exp2f((a4[3] + bv) * K2F), 60000.f);
        }
        __syncthreads();
        // copy-out: row-major, coalesced 16B stores
        {
            const int row = tid >> 2, seg = tid & 3;
            half8 v0 = *(const half8*)&ltb[row][seg * 16];
            half8 v1 = *(const half8*)&ltb[row][seg * 16 + 8];
            _Float16* dst = &ytr[(size_t)(R0 + row) * D_ + colq * 64 + seg * 16];
            *(half8*)&dst[0] = v0;
            *(half8*)&dst[8] = v1;
        }
    } else {
        int row  = (bid - 256) * 4 + w;
        float p0 = 0.f, p1 = 0.f;
        #pragma unroll
        for (int i = 0; i < 4; i++) {
            int d = lane + i * 64;
            float v = tgt[row * D_ + d];
            float2 wv = *(const float2*)&Wp[d * 2];
            p0 = fmaf(v, wv.x, p0);
            p1 = fmaf(v, wv.y, p1);
        }
        #pragma unroll
        for (int off = 32; off > 0; off >>= 1) {
            p0 += __shfl_down(p0, off, 64);
            p1 += __shfl_down(p1, off, 64);
        }
        if (lane == 0) {
            const float L2E = 1.4426950408889634f;
            float l0 = p0 + bp[0], l1 = p1 + bp[1];
            float e10 = __builtin_amdgcn_exp2f((l1 - l0) * L2E);
            float e01 = __builtin_amdgcn_exp2f((l0 - l1) * L2E);
            out[B_ * T_ * S_ + row * 2 + 0] = __builtin_amdgcn_rcpf(1.f + e10);
            out[B_ * T_ * S_ + row * 2 + 1] = __builtin_amdgcn_rcpf(1.f + e01);
        }
    }
}

// ---------------------------------------------------------------------------
// K2: genp v8 — v1's proven shape (32s x 32t tile, 2s x 2t/thread, full d,
// dbuf, plain stores, 1024 blocks = 4 blk/CU) with f16 row-major LDS:
// one ds_read_b128 = 8 d's for one row -> 128 reads/thread vs v1's 512 b64
// (LDS floor 20.5 -> 10.2us). No atomics (R11 lesson), no d-split.
// Thread rows: s = m, m+16; t = g, g+16 (paired rows 16 apart land on the
// SAME bank group at stride-72-halves -> <=2-way aliasing = free; adjacent
// pairing 2m/2m+1 would be 4-way). Stage: 8KB/chunk, 2x16B per thread.
// genP = C0 - 2 * sum_d w_d / (1 + ys*yt),  C0 = sum w + b_res.
// ---------------------------------------------------------------------------
__global__ __launch_bounds__(256) void genp_kernel(
    const _Float16* __restrict__ ytr,   // [4096][256]
    const float* __restrict__ Wres, const float* __restrict__ bres,
    float* __restrict__ out)
{
    __shared__ _Float16 lys[2][32][72];   // 9.2 KB
    __shared__ _Float16 lyt[2][32][72];   // 9.2 KB

    const int tid = threadIdx.x;
    const int lane = tid & 63;
    const int s0 = blockIdx.x * 32;
    const int t0 = blockIdx.y * 32;
    const int b  = blockIdx.z;
    const int m  = tid & 15;             // s rows m, m+16
    const int g  = tid >> 4;             // t rows g, g+16

    // staging: thread stages one 16B chunk of lys and one of lyt per chunk
    const int srow = tid & 31;           // tile row 0..31
    const int sq   = (tid >> 5) & 7;     // 16B (8-half) chunk 0..7
    const size_t gsbase = (size_t)(b * S_ + s0 + srow) * D_;
    const size_t gtbase = (size_t)(NSRC + b * T_ + t0 + srow) * D_;

    half8 pvs = *(const half8*)&ytr[gsbase + 8 * sq];
    half8 pvt = *(const half8*)&ytr[gtbase + 8 * sq];
    *(half8*)&lys[0][srow][8 * sq] = pvs;
    *(half8*)&lyt[0][srow][8 * sq] = pvt;
    __syncthreads();

    f32x2 acc[2];                        // [t-row i]; lanes = (s=m, s=m+16)
    acc[0] = (f32x2){0.f, 0.f};
    acc[1] = (f32x2){0.f, 0.f};
    const f32x2 one2 = {1.f, 1.f};

    for (int c = 0; c < 4; c++) {
        const int bi = c & 1;
        half8 nvs, nvt;
        if (c < 3) {
            nvs = *(const half8*)&ytr[gsbase + (c + 1) * 64 + 8 * sq];
            nvt = *(const half8*)&ytr[gtbase + (c + 1) * 64 + 8 * sq];
        }
        const float* wp = &Wres[c * 64];
        #pragma unroll 2
        for (int kq = 0; kq < 8; kq++) {
            half8 sL = *(const half8*)&lys[bi][m][8 * kq];
            half8 sH = *(const half8*)&lys[bi][m + 16][8 * kq];
            half8 tL = *(const half8*)&lyt[bi][g][8 * kq];
            half8 tH = *(const half8*)&lyt[bi][g + 16][8 * kq];
            f32x2 sp[8];
            float tLf[8], tHf[8];
            f32x2 wv[8];
            #pragma unroll
            for (int k = 0; k < 8; k++) {
                sp[k] = (f32x2){(float)sL[k], (float)sH[k]};
                tLf[k] = (float)tL[k];
                tHf[k] = (float)tH[k];
                const float wk = wp[kq * 8 + k];     // uniform s_load
                wv[k] = (f32x2){wk, wk};
            }
            // 8-term rcp fold (proven math), once per t-row
            #define FOLD(TT, TF) {                                            \
                f32x2 dd[8];                                                  \
                _Pragma("unroll")                                             \
                for (int k = 0; k < 8; k++) {                                 \
                    const f32x2 cs2 = {TF[k], TF[k]};                         \
                    dd[k] = sp[k] * cs2 + one2;                               \
                }                                                             \
                f32x2 p01 = dd[0] * dd[1];                                    \
                f32x2 p23 = dd[2] * dd[3];                                    \
                f32x2 p45 = dd[4] * dd[5];                                    \
                f32x2 p67 = dd[6] * dd[7];                                    \
                f32x2 q03 = p01 * p23;                                        \
                f32x2 q47 = p45 * p67;                                        \
                f32x2 den = q03 * q47;                                        \
                f32x2 u01 = dd[1] * wv[0]; u01 = dd[0] * wv[1] + u01;         \
                f32x2 u23 = dd[3] * wv[2]; u23 = dd[2] * wv[3] + u23;         \
                f32x2 u45 = dd[5] * wv[4]; u45 = dd[4] * wv[5] + u45;         \
                f32x2 u67 = dd[7] * wv[6]; u67 = dd[6] * wv[7] + u67;         \
                f32x2 n03 = u01 * p23; n03 = u23 * p01 + n03;                 \
                f32x2 n47 = u45 * p67; n47 = u67 * p45 + n47;                 \
                f32x2 num = n03 * q47; num = n47 * q03 + num;                 \
                f32x2 rr;                                                     \
                rr.x = __builtin_amdgcn_rcpf(den.x);                          \
                rr.y = __builtin_amdgcn_rcpf(den.y);                          \
                acc[TT] = num * rr + acc[TT];                                 \
            }
            FOLD(0, tLf) FOLD(1, tHf)
            #undef FOLD
        }
        if (c < 3) {
            *(half8*)&lys[bi ^ 1][srow][8 * sq] = nvs;
            *(half8*)&lyt[bi ^ 1][srow][8 * sq] = nvt;
        }
        __syncthreads();
    }

    // C0 per-wave butterfly (no LDS), plain stores (no atomics)
    float cw = Wres[lane] + Wres[lane + 64] + Wres[lane + 128] + Wres[lane + 192];
    #pragma unroll
    for (int off = 32; off > 0; off >>= 1) cw += __shfl_xor(cw, off, 64);
    const float C0 = cw + bres[0];

    out[(size_t)(b * T_ + t0 + g     ) * S_ + s0 + m     ] = C0 - 2.f * acc[0].x;
    out[(size_t)(b * T_ + t0 + g     ) * S_ + s0 + m + 16] = C0 - 2.f * acc[0].y;
    out[(size_t)(b * T_ + t0 + g + 16) * S_ + s0 + m     ] = C0 - 2.f * acc[1].x;
    out[(size_t)(b * T_ + t0 + g + 16) * S_ + s0 + m + 16] = C0 - 2.f * acc[1].y;
}

extern "C" void kernel_launch(void* const* d_in, const int* in_sizes, int n_in,
                              void* d_out, int out_size, void* d_ws, size_t ws_size,
                              hipStream_t stream) {
    const float* source = (const float*)d_in[0];
    const float* target = (const float*)d_in[1];
    const float* W_src  = (const float*)d_in[2];
    const float* b_src  = (const float*)d_in[3];
    const float* W_tgt  = (const float*)d_in[4];
    const float* b_tgt  = (const float*)d_in[5];
    const float* W_res  = (const float*)d_in[6];
    const float* b_res  = (const float*)d_in[7];
    const float* W_prob = (const float*)d_in[8];
    const float* b_prob = (const float*)d_in[9];
    float* out = (float*)d_out;

    _Float16* ytr = (_Float16*)d_ws;           // [4096][256] f16 = 2 MB

    ysyt_kernel<<<768, 256, 0, stream>>>(source, target, W_src, W_tgt,
                                         W_prob, b_prob, b_src, b_tgt,
                                         ytr, out);
    genp_kernel<<<dim3(16, 16, 4), 256, 0, stream>>>(ytr, W_res, b_res, out);
}

// Round 13
// 107.552 us; speedup vs baseline: 1.3727x; 1.0081x over previous
//
#include <hip/hip_runtime.h>

#define B_ 4
#define S_ 512
#define T_ 512
#define D_ 256
#define NSRC (B_ * S_)            // 2048 source rows
#define NROW 4096                 // src rows + tgt rows
#define K2F 2.8853900817779268f   // 2*log2(e): exp2(x*K2F) = e^(2x)

typedef __attribute__((ext_vector_type(8))) short short8;      // 8 bf16
typedef __attribute__((ext_vector_type(8))) _Float16 half8;    // 8 f16
typedef __attribute__((ext_vector_type(4))) float f32x4;
typedef __attribute__((ext_vector_type(2))) float f32x2;

__device__ __forceinline__ unsigned short f2bf(float f) {
    union { float f; unsigned u; } v; v.f = f;
    unsigned r = v.u + 0x7FFF + ((v.u >> 16) & 1);   // RNE
    return (unsigned short)(r >> 16);
}

// ---------------------------------------------------------------------------
// K1: ysyt+prob (VERBATIM R12, passed with absmax 0.0078). 768 blocks.
//  blocks 0..255: W-slab LDS transpose + MFMA + exp2 -> ROW-MAJOR f16
//    ytr[row][d] via LDS bounce. f16 safe (e^{2u} <= ~8100, clamp 60000).
//  blocks 256..767: prob softmax, 4 rows each.
// ---------------------------------------------------------------------------
__global__ __launch_bounds__(256) void ysyt_kernel(
    const float* __restrict__ src, const float* __restrict__ tgt,
    const float* __restrict__ Wsrc, const float* __restrict__ Wtgt,
    const float* __restrict__ Wp,  const float* __restrict__ bp,
    const float* __restrict__ bsrc, const float* __restrict__ btgt,
    _Float16* __restrict__ ytr, float* __restrict__ out)
{
    __shared__ unsigned short lwt[16384];    // 32 KB
    __shared__ _Float16 ltb[64][72];         // 9.2 KB bounce tile
    const int bid = blockIdx.x, tid = threadIdx.x;
    const int lane = tid & 63, w = tid >> 6;

    if (bid < 256) {
        const int rowblk = bid >> 2, colq = bid & 3;
        const int R0 = rowblk * 64;
        const int n = lane & 15, quad = lane >> 4;
        const int mat = (R0 >= NSRC) ? 1 : 0;
        const float* bias = mat ? btgt : bsrc;
        const float* Wm = mat ? Wtgt : Wsrc;
        const float* xb = mat ? &tgt[(R0 - NSRC) * D_] : &src[R0 * D_];

        {   // W-slab transpose -> lwt (verbatim R9)
            const int r = tid;
            const int ksr = r >> 5, qr = (r >> 3) & 3, jr = r & 7;
            const int wbase = ksr * 512 + qr * 8 + jr;
            #pragma unroll 4
            for (int i = 0; i < 16; i++) {
                float4 v = *(const float4*)&Wm[r * D_ + colq * 64 + 4 * i];
                const int cc = 4 * i;
                lwt[((cc + 0) >> 4) * 4096 + ((cc + 0) & 15) * 32 + wbase] = f2bf(v.x);
                lwt[((cc + 1) >> 4) * 4096 + ((cc + 1) & 15) * 32 + wbase] = f2bf(v.y);
                lwt[((cc + 2) >> 4) * 4096 + ((cc + 2) & 15) * 32 + wbase] = f2bf(v.z);
                lwt[((cc + 3) >> 4) * 4096 + ((cc + 3) & 15) * 32 + wbase] = f2bf(v.w);
            }
        }

        short8 af[8];
        #pragma unroll
        for (int ks = 0; ks < 8; ks++) {
            const float* p = &xb[(w * 16 + n) * D_ + ks * 32 + quad * 8];
            float4 u0 = *(const float4*)p;
            float4 u1 = *(const float4*)(p + 4);
            short8 v;
            v[0] = (short)f2bf(u0.x); v[1] = (short)f2bf(u0.y);
            v[2] = (short)f2bf(u0.z); v[3] = (short)f2bf(u0.w);
            v[4] = (short)f2bf(u1.x); v[5] = (short)f2bf(u1.y);
            v[6] = (short)f2bf(u1.z); v[7] = (short)f2bf(u1.w);
            af[ks] = v;
        }
        __syncthreads();

        #pragma unroll
        for (int gc = 0; gc < 4; gc++) {
            const int gcol = colq * 4 + gc;
            const unsigned short* bp2 = &lwt[gc * 4096 + n * 32 + quad * 8];
            short8 bf[8];
            #pragma unroll
            for (int ks = 0; ks < 8; ks++) bf[ks] = *(const short8*)&bp2[ks * 512];
            f32x4 a4 = {0.f, 0.f, 0.f, 0.f};
            #pragma unroll
            for (int ks = 0; ks < 8; ks++)
                a4 = __builtin_amdgcn_mfma_f32_16x16x32_bf16(af[ks], bf[ks], a4, 0, 0, 0);
            const float bv = bias[gcol * 16 + n];
            const int rl = w * 16 + quad * 4;
            const int dl = gc * 16 + n;
            ltb[rl + 0][dl] = (_Float16)fminf(__builtin_amdgcn_exp2f((a4[0] + bv) * K2F), 60000.f);
            ltb[rl + 1][dl] = (_Float16)fminf(__builtin_amdgcn_exp2f((a4[1] + bv) * K2F), 60000.f);
            ltb[rl + 2][dl] = (_Float16)fminf(__builtin_amdgcn_exp2f((a4[2] + bv) * K2F), 60000.f);
            ltb[rl + 3][dl] = (_Float16)fminf(__builtin_amdgcn_exp2f((a4[3] + bv) * K2F), 60000.f);
        }
        __syncthreads();
        {
            const int row = tid >> 2, seg = tid & 3;
            half8 v0 = *(const half8*)&ltb[row][seg * 16];
            half8 v1 = *(const half8*)&ltb[row][seg * 16 + 8];
            _Float16* dst = &ytr[(size_t)(R0 + row) * D_ + colq * 64 + seg * 16];
            *(half8*)&dst[0] = v0;
            *(half8*)&dst[8] = v1;
        }
    } else {
        int row  = (bid - 256) * 4 + w;
        float p0 = 0.f, p1 = 0.f;
        #pragma unroll
        for (int i = 0; i < 4; i++) {
            int d = lane + i * 64;
            float v = tgt[row * D_ + d];
            float2 wv = *(const float2*)&Wp[d * 2];
            p0 = fmaf(v, wv.x, p0);
            p1 = fmaf(v, wv.y, p1);
        }
        #pragma unroll
        for (int off = 32; off > 0; off >>= 1) {
            p0 += __shfl_down(p0, off, 64);
            p1 += __shfl_down(p1, off, 64);
        }
        if (lane == 0) {
            const float L2E = 1.4426950408889634f;
            float l0 = p0 + bp[0], l1 = p1 + bp[1];
            float e10 = __builtin_amdgcn_exp2f((l1 - l0) * L2E);
            float e01 = __builtin_amdgcn_exp2f((l0 - l1) * L2E);
            out[B_ * T_ * S_ + row * 2 + 0] = __builtin_amdgcn_rcpf(1.f + e10);
            out[B_ * T_ * S_ + row * 2 + 1] = __builtin_amdgcn_rcpf(1.f + e01);
        }
    }
}

// ---------------------------------------------------------------------------
// K2: genp v9 — SINGLE-BARRIER full-D stage.
// R12 lesson: v1/v3/v8 all ~30us despite 2x LDS-floor cuts -> bound by the
// 4x {stage -> barrier -> compute} convoy, not by LDS/VALU issue. With f16
// the whole 32s+32t x 256d tile = 32KB fits LDS at 4 blk/CU: stage ONCE
// (8x16B/thread, 512B-contiguous runs), ONE barrier, then 32 kq iterations
// of pure LDS+VALU -- zero barriers, zero global loads in the loop.
// Tile 32s x 32t, grid (16,16,4) = 1024 blocks, 256 thr, 4 blk/CU
// (LDS 33.8KB). Thread: s rows m,m+16; t rows g,g+16 (stride 264 halves =
// 132 words: 16 lanes -> 8 banks x 2-way = free, m136). Proven v8 fold.
// genP = C0 - 2 * sum_d w_d / (1 + ys*yt),  C0 = sum w + b_res.
// ---------------------------------------------------------------------------
__global__ __launch_bounds__(256) void genp_kernel(
    const _Float16* __restrict__ ytr,   // [4096][256]
    const float* __restrict__ Wres, const float* __restrict__ bres,
    float* __restrict__ out)
{
    __shared__ _Float16 lys[32][264];   // 16.9 KB
    __shared__ _Float16 lyt[32][264];   // 16.9 KB

    const int tid = threadIdx.x;
    const int lane = tid & 63;
    const int s0 = blockIdx.x * 32;
    const int t0 = blockIdx.y * 32;
    const int b  = blockIdx.z;
    const int m  = tid & 15;             // s rows m, m+16
    const int g  = tid >> 4;             // t rows g, g+16  (0..15)

    // ---- stage ALL 256 d in one burst: thread = (row, 64B-seg) ----
    {
        const int srow = tid >> 3;       // 0..31
        const int seg  = tid & 7;        // 0..7, 32 halves each
        const size_t gs = (size_t)(b * S_ + s0 + srow) * D_ + seg * 32;
        const size_t gt = (size_t)(NSRC + b * T_ + t0 + srow) * D_ + seg * 32;
        #pragma unroll
        for (int j = 0; j < 4; j++) {
            *(half8*)&lys[srow][seg * 32 + 8 * j] = *(const half8*)&ytr[gs + 8 * j];
            *(half8*)&lyt[srow][seg * 32 + 8 * j] = *(const half8*)&ytr[gt + 8 * j];
        }
    }
    __syncthreads();                     // the ONLY barrier

    f32x2 acc[2];                        // [t-row i]; lanes = (s=m, s=m+16)
    acc[0] = (f32x2){0.f, 0.f};
    acc[1] = (f32x2){0.f, 0.f};
    const f32x2 one2 = {1.f, 1.f};

    #pragma unroll 4
    for (int kq = 0; kq < 32; kq++) {
        half8 sL = *(const half8*)&lys[m][8 * kq];
        half8 sH = *(const half8*)&lys[m + 16][8 * kq];
        half8 tL = *(const half8*)&lyt[g][8 * kq];
        half8 tH = *(const half8*)&lyt[g + 16][8 * kq];
        f32x2 sp[8];
        float tLf[8], tHf[8];
        f32x2 wv[8];
        #pragma unroll
        for (int k = 0; k < 8; k++) {
            sp[k] = (f32x2){(float)sL[k], (float)sH[k]};
            tLf[k] = (float)tL[k];
            tHf[k] = (float)tH[k];
            const float wk = Wres[kq * 8 + k];       // uniform s_load
            wv[k] = (f32x2){wk, wk};
        }
        // 8-term rcp fold (proven math), once per t-row
        #define FOLD(TT, TF) {                                            \
            f32x2 dd[8];                                                  \
            _Pragma("unroll")                                             \
            for (int k = 0; k < 8; k++) {                                 \
                const f32x2 cs2 = {TF[k], TF[k]};                         \
                dd[k] = sp[k] * cs2 + one2;                               \
            }                                                             \
            f32x2 p01 = dd[0] * dd[1];                                    \
            f32x2 p23 = dd[2] * dd[3];                                    \
            f32x2 p45 = dd[4] * dd[5];                                    \
            f32x2 p67 = dd[6] * dd[7];                                    \
            f32x2 q03 = p01 * p23;                                        \
            f32x2 q47 = p45 * p67;                                        \
            f32x2 den = q03 * q47;                                        \
            f32x2 u01 = dd[1] * wv[0]; u01 = dd[0] * wv[1] + u01;         \
            f32x2 u23 = dd[3] * wv[2]; u23 = dd[2] * wv[3] + u23;         \
            f32x2 u45 = dd[5] * wv[4]; u45 = dd[4] * wv[5] + u45;         \
            f32x2 u67 = dd[7] * wv[6]; u67 = dd[6] * wv[7] + u67;         \
            f32x2 n03 = u01 * p23; n03 = u23 * p01 + n03;                 \
            f32x2 n47 = u45 * p67; n47 = u67 * p45 + n47;                 \
            f32x2 num = n03 * q47; num = n47 * q03 + num;                 \
            f32x2 rr;                                                     \
            rr.x = __builtin_amdgcn_rcpf(den.x);                          \
            rr.y = __builtin_amdgcn_rcpf(den.y);                          \
            acc[TT] = num * rr + acc[TT];                                 \
        }
        FOLD(0, tLf) FOLD(1, tHf)
        #undef FOLD
    }

    // C0 per-wave butterfly (no LDS), plain stores (no atomics)
    float cw = Wres[lane] + Wres[lane + 64] + Wres[lane + 128] + Wres[lane + 192];
    #pragma unroll
    for (int off = 32; off > 0; off >>= 1) cw += __shfl_xor(cw, off, 64);
    const float C0 = cw + bres[0];

    out[(size_t)(b * T_ + t0 + g     ) * S_ + s0 + m     ] = C0 - 2.f * acc[0].x;
    out[(size_t)(b * T_ + t0 + g     ) * S_ + s0 + m + 16] = C0 - 2.f * acc[0].y;
    out[(size_t)(b * T_ + t0 + g + 16) * S_ + s0 + m     ] = C0 - 2.f * acc[1].x;
    out[(size_t)(b * T_ + t0 + g + 16) * S_ + s0 + m + 16] = C0 - 2.f * acc[1].y;
}

extern "C" void kernel_launch(void* const* d_in, const int* in_sizes, int n_in,
                              void* d_out, int out_size, void* d_ws, size_t ws_size,
                              hipStream_t stream) {
    const float* source = (const float*)d_in[0];
    const float* target = (const float*)d_in[1];
    const float* W_src  = (const float*)d_in[2];
    const float* b_src  = (const float*)d_in[3];
    const float* W_tgt  = (const float*)d_in[4];
    const float* b_tgt  = (const float*)d_in[5];
    const float* W_res  = (const float*)d_in[6];
    const float* b_res  = (const float*)d_in[7];
    const float* W_prob = (const float*)d_in[8];
    const float* b_prob = (const float*)d_in[9];
    float* out = (float*)d_out;

    _Float16* ytr = (_Float16*)d_ws;           // [4096][256] f16 = 2 MB

    ysyt_kernel<<<768, 256, 0, stream>>>(source, target, W_src, W_tgt,
                                         W_prob, b_prob, b_src, b_tgt,
                                         ytr, out);
    genp_kernel<<<dim3(16, 16, 4), 256, 0, stream>>>(ytr, W_res, b_res, out);
}